// Round 8
// baseline (162.752 us; speedup 1.0000x reference)
//
#include <hip/hip_runtime.h>
#include <math.h>

// B=4096, T=64, C=64, H=8, D=8. fp32 in/out.
// d_ws fp16: WqkvT[n][c] (n: q 0-63 | k 64-127 | v 128-191), then W1T[j][c].
// Wk section is PRE-SCALED by C^-0.5*log2(e) so softmax is exp2(S) directly.
// Main kernel: 256 thr (4 waves) per batch element, 6 blocks/CU (LDS padded
// to 24576B; 8 blocks/CU thrashes per-XCD L2 -> write amplification, R3/R4).
// Wave w owns heads 2w,2w+1 end-to-end (phase-1 m-tiles {w,4+w,8+w}).
// R6/R7 lesson: keeping Q in registers across phase 2 (qp[4] live through
// the longest phase) triggers scratch spill traffic (+29MB HBM writes) and
// +10us, despite reported VGPR=40. Q goes through LDS (ah) as in R5;
// K stays in regs (kp liveness there measured clean in R5).
//  phase0: x -> fp16 LDS xs[64][72]        (region0)
//  phase1: QKV^T = Wqkv^T x^T (16x16x32_f16), x-frags cached in regs.
//          Q -> ah LDS (wave-private rows), K -> kp regs, V accs -> vth
//          after the xs barrier. No barrier after (all wave-private).
//  phase2: per head (serial hh): S^T = K Q^T (triangular 16x16x16f16);
//          CAUSAL MASK VIA C-INIT: diagonal tile's MFMA C = -30000 on
//          masked lanes, exp2 flushes to 0 (deletes 32 cndmask/thread).
//          DENOMINATOR VIA ONES-ROW: V^T A-frag row 8 (l15==8) = 1.0h, so
//          PV output row 8 (lane quad2,r0) = sum_s P[s][t]; normalize =
//          1 ds_bpermute + rcp per (hh,tn) (deletes 80 adds + 16 shfl_xor
//          per thread). Packed P IS the PV B-frag (k=4q+j == S^T C-layout).
//  phase3: y^T = W1^T att^T. Wave w owns t-ROWS 16w..16w+15: each 128B
//          y line written entirely by one wave (no half-dirty-line RMW).
// LDS: region0 9216 (xs|vth) + ah 8192+7168pad = 24576 B -> 6 blocks/CU.

typedef __attribute__((ext_vector_type(8))) __fp16 half8;
typedef __attribute__((ext_vector_type(4))) __fp16 half4;
typedef __attribute__((ext_vector_type(2))) __fp16 half2v;
typedef __attribute__((ext_vector_type(4))) float f32x4;

__global__ void prep_weights(const float* __restrict__ Wq,
                             const float* __restrict__ Wk,
                             const float* __restrict__ Wv,
                             const float* __restrict__ W1,
                             __fp16* __restrict__ ws)
{
    int i = blockIdx.x * 256 + threadIdx.x;      // 16384 total
    if (i < 12288) {
        int n = i >> 6, c = i & 63;
        int sec = n >> 6;
        const float* src = (sec == 0) ? Wq : (sec == 1) ? Wk : Wv;
        int h = (n & 63) >> 3, d = n & 7;
        float v = src[h * 512 + c * 8 + d];
        if (sec == 1) v *= 0.18033688011112042f;   // C^-0.5 * log2(e) into K
        ws[i] = (__fp16)v;
    } else {
        int j = (i - 12288) >> 6, c = i & 63;
        ws[i] = (__fp16)W1[c * 64 + j];
    }
}

__device__ __forceinline__ uint32_t pk2h(float a, float b) {
    half2v h = __builtin_amdgcn_cvt_pkrtz(a, b);
    union { half2v h; uint32_t u; } c;
    c.h = h;
    return c.u;
}

__device__ __forceinline__ half4 as_h4(uint2 u) {
    union { uint2 u; half4 h; } c;
    c.u = u;
    return c.h;
}

__global__ __launch_bounds__(256, 6) void mha_mfma4_kernel(
    const float* __restrict__ x,
    const __fp16* __restrict__ wT,
    const float* __restrict__ b1v,
    float* __restrict__ y)
{
    __shared__ __align__(16) __fp16 region0[64 * 72];      // xs, later vth
    __shared__ __align__(16) __fp16 ah[8 * 64 * 8 + 3584]; // Q->att (+pad to
                                                           // 24576B total:
                                                           // pins 6 blk/CU)

    __fp16* xs  = region0;            // [64][72]
    __fp16* vth = region0;            // V^T[h][d][s], [64][72] overlay

    const int b    = blockIdx.x;
    const int tid  = threadIdx.x;
    const int lane = tid & 63;
    const int w    = tid >> 6;
    const int l15  = lane & 15;
    const int quad = lane >> 4;

    // ---------------- phase 0: stage x -> fp16 ----------------
    {
        int r = tid >> 2, c0 = (tid & 3) * 16;
        const float* xp = x + (size_t)b * 4096 + r * 64 + c0;
        float4 f0 = ((const float4*)xp)[0];
        float4 f1 = ((const float4*)xp)[1];
        float4 f2 = ((const float4*)xp)[2];
        float4 f3 = ((const float4*)xp)[3];
        union { half2v h2[4]; float4 f; } u0, u1;
        u0.h2[0] = __builtin_amdgcn_cvt_pkrtz(f0.x, f0.y);
        u0.h2[1] = __builtin_amdgcn_cvt_pkrtz(f0.z, f0.w);
        u0.h2[2] = __builtin_amdgcn_cvt_pkrtz(f1.x, f1.y);
        u0.h2[3] = __builtin_amdgcn_cvt_pkrtz(f1.z, f1.w);
        u1.h2[0] = __builtin_amdgcn_cvt_pkrtz(f2.x, f2.y);
        u1.h2[1] = __builtin_amdgcn_cvt_pkrtz(f2.z, f2.w);
        u1.h2[2] = __builtin_amdgcn_cvt_pkrtz(f3.x, f3.y);
        u1.h2[3] = __builtin_amdgcn_cvt_pkrtz(f3.z, f3.w);
        *(float4*)&xs[r * 72 + c0]     = u0.f;
        *(float4*)&xs[r * 72 + c0 + 8] = u1.f;
    }
    __syncthreads();

    // ------- phase 1: QKV^T = Wqkv^T x^T (own heads) -----------------------
    uint2 kp[4];      // packed K: tile tt over s; head by quad pair
    f32x4 vacc[4];    // V accs, stored to vth after the barrier
    {
        half8 xfr0[4], xfr1[4];   // x B-frags, shared by Q/K/V
        #pragma unroll
        for (int tt = 0; tt < 4; ++tt) {
            xfr0[tt] = *(const half8*)&xs[(16 * tt + l15) * 72 + 8 * quad];
            xfr1[tt] = *(const half8*)&xs[(16 * tt + l15) * 72 + 32 + 8 * quad];
        }
        const __fp16* aq = wT + (16 * w + l15) * 64 + 8 * quad;
        const __fp16* ak = wT + (16 * (4 + w) + l15) * 64 + 8 * quad;
        const __fp16* av = wT + (16 * (8 + w) + l15) * 64 + 8 * quad;
        half8 aq0 = *(const half8*)aq;
        half8 aq1 = *(const half8*)(aq + 32);
        half8 ak0 = *(const half8*)ak;
        half8 ak1 = *(const half8*)(ak + 32);
        half8 av0 = *(const half8*)av;
        half8 av1 = *(const half8*)(av + 32);
        #pragma unroll
        for (int tt = 0; tt < 4; ++tt) {
            f32x4 aQ = {0.f, 0.f, 0.f, 0.f};
            f32x4 aK = {0.f, 0.f, 0.f, 0.f};
            f32x4 aV = {0.f, 0.f, 0.f, 0.f};
            aQ = __builtin_amdgcn_mfma_f32_16x16x32_f16(aq0, xfr0[tt], aQ, 0, 0, 0);
            aQ = __builtin_amdgcn_mfma_f32_16x16x32_f16(aq1, xfr1[tt], aQ, 0, 0, 0);
            aK = __builtin_amdgcn_mfma_f32_16x16x32_f16(ak0, xfr0[tt], aK, 0, 0, 0);
            aK = __builtin_amdgcn_mfma_f32_16x16x32_f16(ak1, xfr1[tt], aK, 0, 0, 0);
            aV = __builtin_amdgcn_mfma_f32_16x16x32_f16(av0, xfr0[tt], aV, 0, 0, 0);
            aV = __builtin_amdgcn_mfma_f32_16x16x32_f16(av1, xfr1[tt], aV, 0, 0, 0);
            int t = 16 * tt + l15;
            union { uint32_t u2[2]; uint2 u; } pq;
            pq.u2[0] = pk2h(aQ[0], aQ[1]);
            pq.u2[1] = pk2h(aQ[2], aQ[3]);
            *(uint2*)&ah[((2 * w + (quad >> 1)) * 64 + t) * 8 + 4 * (quad & 1)] = pq.u;
            kp[tt].x = pk2h(aK[0], aK[1]);
            kp[tt].y = pk2h(aK[2], aK[3]);
            vacc[tt] = aV;
        }
    }
    __syncthreads();    // all waves done READING xs; region0 -> vth
    {
        int hv = 2 * w + (quad >> 1), d0 = 4 * (quad & 1);
        #pragma unroll
        for (int tt = 0; tt < 4; ++tt) {
            int t = 16 * tt + l15;
            #pragma unroll
            for (int r = 0; r < 4; ++r)
                vth[(hv * 8 + d0 + r) * 72 + t] = (__fp16)vacc[tt][r];
        }
    }
    // vth rows 16w..16w+15 are wave-private: NO barrier before phase 2.

    const half4 z4 = {};
    const half4 ones4 = {(__fp16)1.0f, (__fp16)1.0f, (__fp16)1.0f, (__fp16)1.0f};
    // causal mask as MFMA C-init for the diagonal tile: exp2 flushes to 0
    f32x4 mdiag;
    #pragma unroll
    for (int r = 0; r < 4; ++r)
        mdiag[r] = (4 * quad + r > l15) ? -30000.f : 0.f;

    // ---------------- phase 2: attention, heads h = 2w, 2w+1 (SERIAL) ------
    // 16x16x16f16: A k=4q+j, B k=4q+j, D row=4q+r col=l15.
    // Head 2w in k-slots 0-7 (quads 0,1); head 2w+1 in k-slots 8-15 (2,3).
    // K is masked per head (A zeros kill the other head's Q half in B).
    // V^T A-frag: rows 0-7 = V, row 8 = ONES -> PV output row 8 (lane
    // quad2,r0) = column sums of P = softmax denominator, free via MFMA.
    #pragma unroll 1
    for (int hh = 0; hh < 2; ++hh) {
        const int h = 2 * w + hh;
        const bool act = ((quad >> 1) == hh);
        half4 kfr[4], vfr[4];
        #pragma unroll
        for (int tm = 0; tm < 4; ++tm) {
            uint2 kv;
            kv.x = act ? kp[tm].x : 0u;
            kv.y = act ? kp[tm].y : 0u;
            kfr[tm] = as_h4(kv);
        }
        #pragma unroll
        for (int km = 0; km < 4; ++km)   // A-frag of V^T: m=d=l15(<8), k=s; row8=1s
            vfr[km] = (l15 < 8)
                ? *(const half4*)&vth[(h * 8 + l15) * 72 + 16 * km + 4 * quad]
                : (l15 == 8 ? ones4 : z4);

        #pragma unroll
        for (int tn = 0; tn < 4; ++tn) {
            half4 qf = act
                ? *(const half4*)&ah[(h * 64 + 16 * tn + l15) * 8 + 4 * (quad & 1)]
                : z4;

            f32x4 S[4];   // S^T tiles in column tn, tm <= tn
            #pragma unroll
            for (int tm = 0; tm <= tn; ++tm) {
                f32x4 ci = (tm == tn) ? mdiag : f32x4{0.f, 0.f, 0.f, 0.f};
                S[tm] = __builtin_amdgcn_mfma_f32_16x16x16f16(kfr[tm], qf, ci, 0, 0, 0);
            }

            // max-free softmax; scale pre-folded into K; mask pre-folded in C
            #pragma unroll
            for (int tm = 0; tm <= tn; ++tm)
                #pragma unroll
                for (int r = 0; r < 4; ++r)
                    S[tm][r] = __builtin_exp2f(S[tm][r]);

            // O^T col tn: packed P IS the B-frag. Row 8 of O = denominator.
            f32x4 O = {0.f, 0.f, 0.f, 0.f};
            #pragma unroll
            for (int km = 0; km <= tn; ++km) {
                uint2 pu;
                pu.x = pk2h(S[km][0], S[km][1]);
                pu.y = pk2h(S[km][2], S[km][3]);
                O = __builtin_amdgcn_mfma_f32_16x16x16f16(vfr[km], as_h4(pu), O, 0, 0, 0);
            }

            // denominator lives in lane (quad=2, r=0) of this column
            float ls  = __shfl(O[0], 32 + l15);
            float inv = __builtin_amdgcn_rcpf(ls);

            // O^T row d=4q+r (valid q<2), col t=16tn+l15; normalize, store att
            if (quad < 2) {
                union { uint32_t u2[2]; uint2 u; } po;
                po.u2[0] = pk2h(O[0] * inv, O[1] * inv);
                po.u2[1] = pk2h(O[2] * inv, O[3] * inv);
                *(uint2*)&ah[(h * 64 + 16 * tn + l15) * 8 + 4 * quad] = po.u;
            }
        }
    }
    __syncthreads();

    // ---------------- phase 3: y^T = W1^T att^T, row-block per wave --------
    // Wave w: t = 16w + l15 (fixed), j-tiles mt=0..3. B-frags loop-invariant.
    // Each y 128B line written entirely by this wave.
    {
        half8 bq0 = *(const half8*)&ah[(quad * 64 + 16 * w + l15) * 8];       // k: h=quad
        half8 bq1 = *(const half8*)&ah[((4 + quad) * 64 + 16 * w + l15) * 8]; // k: h=4+quad
        float* yb = y + (size_t)b * 4096 + (16 * w + l15) * 64;
        #pragma unroll
        for (int mt = 0; mt < 4; ++mt) {
            const __fp16* wp = wT + 12288 + (16 * mt + l15) * 64 + 8 * quad;
            half8 w0 = *(const half8*)wp;
            half8 w1 = *(const half8*)(wp + 32);
            float4 bias4 = *(const float4*)&b1v[16 * mt + 4 * quad];
            f32x4 acc = {0.f, 0.f, 0.f, 0.f};
            acc = __builtin_amdgcn_mfma_f32_16x16x32_f16(w0, bq0, acc, 0, 0, 0);
            acc = __builtin_amdgcn_mfma_f32_16x16x32_f16(w1, bq1, acc, 0, 0, 0);
            float4 o;
            o.x = fmaxf(acc[0] + bias4.x, 0.f);
            o.y = fmaxf(acc[1] + bias4.y, 0.f);
            o.z = fmaxf(acc[2] + bias4.z, 0.f);
            o.w = fmaxf(acc[3] + bias4.w, 0.f);
            *(float4*)&yb[16 * mt + 4 * quad] = o;
        }
    }
}

extern "C" void kernel_launch(void* const* d_in, const int* in_sizes, int n_in,
                              void* d_out, int out_size, void* d_ws, size_t ws_size,
                              hipStream_t stream) {
    const float* x  = (const float*)d_in[0];
    const float* Wq = (const float*)d_in[1];
    const float* Wk = (const float*)d_in[2];
    const float* Wv = (const float*)d_in[3];
    const float* W1 = (const float*)d_in[4];
    const float* b1 = (const float*)d_in[5];
    float* y = (float*)d_out;
    __fp16* ws = (__fp16*)d_ws;

    const int B = in_sizes[0] / 4096;   // 4096
    prep_weights<<<64, 256, 0, stream>>>(Wq, Wk, Wv, W1, ws);
    mha_mfma4_kernel<<<B, 256, 0, stream>>>(x, ws, b1, y);
}

// Round 9
// 140.654 us; speedup vs baseline: 1.1571x; 1.1571x over previous
//
#include <hip/hip_runtime.h>
#include <math.h>

// B=4096, T=64, C=64, H=8, D=8. fp32 in/out.
// d_ws fp16: WqkvT[n][c] (n: q 0-63 | k 64-127 | v 128-191), then W1T[j][c].
// Wk section PRE-SCALED by C^-0.5*log2(e) so softmax is exp2(S) directly
// (deletes 80 v_mul/thread; weight-side transform, zero liveness cost).
// Main kernel: 256 thr (4 waves) per batch element, 6 blocks/CU (LDS 25600B).
// STRUCTURE = R2, the measured optimum of this session (51.1us). R3-R8
// lesson: every phase-2 liveness restructure (K/Q in regs, head braid,
// mask-in-C, MFMA-computed denominator) triggered scratch-spill-signature
// HBM traffic (+20..49MB writes) and regressed 13-45%. The all-LDS-staged
// serial form is what the allocator/scheduler handles cleanly. 8 blocks/CU
// also regresses (L2 thrash, R3/R4: write amplification 1.7-2x).
//  phase0: x -> fp16 LDS xs[64][72]       (region0)
//  phase1: QKV^T = Wqkv^T x^T via 16x16x32_f16 (A=weights, B=x frags cached
//          in regs). Packed C -> qh (Q), kh (K); V scalar -> vth (region0
//          overlay, after the xs-consumed barrier). Barrier (cross-wave).
//  phase2: per wave, heads 2w,2w+1 with 16x16x16_f16 (K=16): A/B frags hold
//          k=4*quad+j == the S^T C-layout, so packed softmax output IS the
//          PV B-operand (no shuffle). S^T col tn: tm<=tn triangular MFMAs;
//          max-free softmax e=exp2(s) (scale pre-folded), causal cndmask on
//          diagonal, row-sum in-lane + shfl_xor(16,32); O^T = V^T P;
//          normalize by rcp; att -> qh.
//  phase3: y^T = W1^T att^T (16x16x32_f16) -> float4 stores.
// LDS: region0 9216 (xs|vth) + qh 8192 + kh 8192 = 25600 B -> 6 blocks/CU.

typedef __attribute__((ext_vector_type(8))) __fp16 half8;
typedef __attribute__((ext_vector_type(4))) __fp16 half4;
typedef __attribute__((ext_vector_type(2))) __fp16 half2v;
typedef __attribute__((ext_vector_type(4))) float f32x4;

__global__ void prep_weights(const float* __restrict__ Wq,
                             const float* __restrict__ Wk,
                             const float* __restrict__ Wv,
                             const float* __restrict__ W1,
                             __fp16* __restrict__ ws)
{
    int i = blockIdx.x * 256 + threadIdx.x;      // 16384 total
    if (i < 12288) {
        int n = i >> 6, c = i & 63;
        int sec = n >> 6;
        const float* src = (sec == 0) ? Wq : (sec == 1) ? Wk : Wv;
        int h = (n & 63) >> 3, d = n & 7;
        float v = src[h * 512 + c * 8 + d];
        if (sec == 1) v *= 0.18033688011112042f;   // C^-0.5 * log2(e) into K
        ws[i] = (__fp16)v;
    } else {
        int j = (i - 12288) >> 6, c = i & 63;
        ws[i] = (__fp16)W1[c * 64 + j];
    }
}

__device__ __forceinline__ uint32_t pk2h(float a, float b) {
    half2v h = __builtin_amdgcn_cvt_pkrtz(a, b);
    union { half2v h; uint32_t u; } c;
    c.h = h;
    return c.u;
}

__global__ __launch_bounds__(256, 6) void mha_mfma4_kernel(
    const float* __restrict__ x,
    const __fp16* __restrict__ wT,
    const float* __restrict__ b1v,
    float* __restrict__ y)
{
    __shared__ __align__(16) __fp16 region0[64 * 72]; // xs, later vth
    __shared__ __align__(16) __fp16 qh[8 * 64 * 8];   // Q[h][t][d] -> att
    __shared__ __align__(16) __fp16 kh[8 * 64 * 8];   // K[h][s][d]

    __fp16* xs  = region0;            // [64][72]
    __fp16* vth = region0;            // V^T[h][d][s], [64][72] overlay

    const int b    = blockIdx.x;
    const int tid  = threadIdx.x;
    const int lane = tid & 63;
    const int w    = tid >> 6;
    const int l15  = lane & 15;
    const int quad = lane >> 4;

    // ---------------- phase 0: stage x -> fp16 ----------------
    {
        int r = tid >> 2, c0 = (tid & 3) * 16;
        const float* xp = x + (size_t)b * 4096 + r * 64 + c0;
        float4 f0 = ((const float4*)xp)[0];
        float4 f1 = ((const float4*)xp)[1];
        float4 f2 = ((const float4*)xp)[2];
        float4 f3 = ((const float4*)xp)[3];
        union { half2v h2[4]; float4 f; } u0, u1;
        u0.h2[0] = __builtin_amdgcn_cvt_pkrtz(f0.x, f0.y);
        u0.h2[1] = __builtin_amdgcn_cvt_pkrtz(f0.z, f0.w);
        u0.h2[2] = __builtin_amdgcn_cvt_pkrtz(f1.x, f1.y);
        u0.h2[3] = __builtin_amdgcn_cvt_pkrtz(f1.z, f1.w);
        u1.h2[0] = __builtin_amdgcn_cvt_pkrtz(f2.x, f2.y);
        u1.h2[1] = __builtin_amdgcn_cvt_pkrtz(f2.z, f2.w);
        u1.h2[2] = __builtin_amdgcn_cvt_pkrtz(f3.x, f3.y);
        u1.h2[3] = __builtin_amdgcn_cvt_pkrtz(f3.z, f3.w);
        *(float4*)&xs[r * 72 + c0]     = u0.f;
        *(float4*)&xs[r * 72 + c0 + 8] = u1.f;
    }
    __syncthreads();

    // ---------------- phase 1: QKV^T = Wqkv^T x^T ----------------
    {
        half8 xfr[4][2];   // B-frags (x)
        #pragma unroll
        for (int tt = 0; tt < 4; ++tt)
            #pragma unroll
            for (int ks = 0; ks < 2; ++ks)
                xfr[tt][ks] = *(const half8*)&xs[(16 * tt + l15) * 72 + 32 * ks + 8 * quad];
        __syncthreads();    // xs fully consumed; region0 now writable as vth

        #pragma unroll
        for (int i = 0; i < 3; ++i) {
            int mt = 3 * w + i;                       // m-tile over n=0..191
            const __fp16* ap = wT + (16 * mt + l15) * 64 + 8 * quad;
            half8 a0 = *(const half8*)ap;
            half8 a1 = *(const half8*)(ap + 32);
            #pragma unroll
            for (int tt = 0; tt < 4; ++tt) {
                f32x4 acc = {0.f, 0.f, 0.f, 0.f};
                acc = __builtin_amdgcn_mfma_f32_16x16x32_f16(a0, xfr[tt][0], acc, 0, 0, 0);
                acc = __builtin_amdgcn_mfma_f32_16x16x32_f16(a1, xfr[tt][1], acc, 0, 0, 0);
                // thread holds n = 16mt+4quad+r, t = 16tt+l15
                int t = 16 * tt + l15;
                union { uint32_t u2[2]; uint2 u; } pq;
                pq.u2[0] = pk2h(acc[0], acc[1]);
                pq.u2[1] = pk2h(acc[2], acc[3]);
                if (mt < 4) {
                    int hq = 2 * mt + (quad >> 1);
                    *(uint2*)&qh[(hq * 64 + t) * 8 + 4 * (quad & 1)] = pq.u;
                } else if (mt < 8) {
                    int hk = 2 * (mt - 4) + (quad >> 1);
                    *(uint2*)&kh[(hk * 64 + t) * 8 + 4 * (quad & 1)] = pq.u;
                } else {
                    int hv = 2 * (mt - 8) + (quad >> 1);
                    int d0 = 4 * (quad & 1);
                    #pragma unroll
                    for (int r = 0; r < 4; ++r)
                        vth[(hv * 8 + d0 + r) * 72 + t] = (__fp16)acc[r];
                }
            }
        }
    }
    __syncthreads();

    const half4 z4 = {};
    const bool dv = (quad < 2);                      // quads holding valid d (0..7)

    // ---------------- phase 2: attention, heads h = 2w, 2w+1 ----------------
    // 16x16x16_f16: A[m][k]: m=l15, k=4*quad+j.  B[k][n]: n=l15, k=4*quad+j.
    // D[row][col]: row=4*quad+r, col=l15.  S^T output layout == PV B-frag layout.
    #pragma unroll 1
    for (int hh = 0; hh < 2; ++hh) {
        const int h = 2 * w + hh;
        half4 kfr[4], vfr[4];
        #pragma unroll
        for (int tm = 0; tm < 4; ++tm)   // A-frag of K: m=s row, k=d=4q+j (q<2)
            kfr[tm] = dv ? *(const half4*)&kh[(h * 64 + 16 * tm + l15) * 8 + 4 * quad] : z4;
        #pragma unroll
        for (int km = 0; km < 4; ++km)   // A-frag of V^T: m=d=l15 (<8), k=s=16km+4q+j
            vfr[km] = (l15 < 8) ? *(const half4*)&vth[(h * 8 + l15) * 72 + 16 * km + 4 * quad] : z4;

        #pragma unroll
        for (int tn = 0; tn < 4; ++tn) {
            half4 qf = dv ? *(const half4*)&qh[(h * 64 + 16 * tn + l15) * 8 + 4 * quad] : z4;

            f32x4 S[4];   // S^T tiles in column tn, tm <= tn
            #pragma unroll
            for (int tm = 0; tm <= tn; ++tm) {
                f32x4 zz = {0.f, 0.f, 0.f, 0.f};
                S[tm] = __builtin_amdgcn_mfma_f32_16x16x16f16(kfr[tm], qf, zz, 0, 0, 0);
            }

            // max-free softmax (scores bounded); scale pre-folded into K
            float ls = 0.f;
            #pragma unroll
            for (int tm = 0; tm <= tn; ++tm)
                #pragma unroll
                for (int r = 0; r < 4; ++r) {
                    float e = __builtin_exp2f(S[tm][r]);
                    if (tm == tn && (4 * quad + r) > l15) e = 0.f;   // causal
                    S[tm][r] = e;
                    ls += e;
                }
            ls += __shfl_xor(ls, 16);
            ls += __shfl_xor(ls, 32);
            float inv = __builtin_amdgcn_rcpf(ls);

            // O^T col tn: packed P IS the B-frag (k=4q+j == s layout). No shuffle.
            f32x4 O = {0.f, 0.f, 0.f, 0.f};
            #pragma unroll
            for (int km = 0; km <= tn; ++km) {
                union { uint32_t u[2]; half4 h4; } bu;
                bu.u[0] = pk2h(S[km][0], S[km][1]);
                bu.u[1] = pk2h(S[km][2], S[km][3]);
                O = __builtin_amdgcn_mfma_f32_16x16x16f16(vfr[km], bu.h4, O, 0, 0, 0);
            }

            // O^T: row d=4q+r (valid for q<2), col t=16tn+l15; normalize by own column sum
            if (dv) {
                union { uint32_t u2[2]; uint2 u; } po;
                po.u2[0] = pk2h(O[0] * inv, O[1] * inv);
                po.u2[1] = pk2h(O[2] * inv, O[3] * inv);
                *(uint2*)&qh[(h * 64 + 16 * tn + l15) * 8 + 4 * quad] = po.u;
            }
        }
    }
    __syncthreads();

    // ---------------- phase 3: y^T = W1^T att^T ----------------
    {
        const __fp16* wp = wT + 12288 + (16 * w + l15) * 64 + 8 * quad;
        half8 w0 = *(const half8*)wp;
        half8 w1 = *(const half8*)(wp + 32);
        float4 bias4 = *(const float4*)&b1v[16 * w + 4 * quad];
        float* yb = y + (size_t)b * 4096;
        #pragma unroll
        for (int tt = 0; tt < 4; ++tt) {
            half8 bq0 = *(const half8*)&qh[(quad * 64 + 16 * tt + l15) * 8];       // k: h=quad
            half8 bq1 = *(const half8*)&qh[((4 + quad) * 64 + 16 * tt + l15) * 8]; // k: h=4+quad
            f32x4 acc = {0.f, 0.f, 0.f, 0.f};
            acc = __builtin_amdgcn_mfma_f32_16x16x32_f16(w0, bq0, acc, 0, 0, 0);
            acc = __builtin_amdgcn_mfma_f32_16x16x32_f16(w1, bq1, acc, 0, 0, 0);
            float4 o;
            o.x = fmaxf(acc[0] + bias4.x, 0.f);
            o.y = fmaxf(acc[1] + bias4.y, 0.f);
            o.z = fmaxf(acc[2] + bias4.z, 0.f);
            o.w = fmaxf(acc[3] + bias4.w, 0.f);
            *(float4*)&yb[(16 * tt + l15) * 64 + 16 * w + 4 * quad] = o;
        }
    }
}

extern "C" void kernel_launch(void* const* d_in, const int* in_sizes, int n_in,
                              void* d_out, int out_size, void* d_ws, size_t ws_size,
                              hipStream_t stream) {
    const float* x  = (const float*)d_in[0];
    const float* Wq = (const float*)d_in[1];
    const float* Wk = (const float*)d_in[2];
    const float* Wv = (const float*)d_in[3];
    const float* W1 = (const float*)d_in[4];
    const float* b1 = (const float*)d_in[5];
    float* y = (float*)d_out;
    __fp16* ws = (__fp16*)d_ws;

    const int B = in_sizes[0] / 4096;   // 4096
    prep_weights<<<64, 256, 0, stream>>>(Wq, Wk, Wv, W1, ws);
    mha_mfma4_kernel<<<B, 256, 0, stream>>>(x, ws, b1, y);
}

// Round 10
// 140.053 us; speedup vs baseline: 1.1621x; 1.0043x over previous
//
#include <hip/hip_runtime.h>
#include <math.h>

// B=4096, T=64, C=64, H=8, D=8. fp32 in/out.
// d_ws fp16: WqkvT[n][c] (n: q 0-63 | k 64-127 | v 128-191), then W1T[j][c].
// Wk section PRE-SCALED by C^-0.5*log2(e) so softmax is exp2(S) directly.
// Main kernel: 256 thr (4 waves) per batch element, 6 blocks/CU (LDS 25600B).
// STRUCTURE = R2/R9, the measured optimum (49.6us). R3-R8 lesson: phase-2
// liveness restructures (K/Q in regs, head braid, mask-in-C, MFMA-denom)
// all triggered scratch-spill-signature HBM traffic and regressed. R10:
// in-place micro-cuts only --
//  (1) ls tree-reduction: pairwise + 2 alternating accumulators (f32 adds
//      can't be compiler-reassociated without fast-math; serial depth 16->5
//      on the exp2->PV critical path),
//  (2) qf loaded RAW (kfr's zero k-slots annihilate B; select deleted),
//  (3) vfr l15-select deleted (garbage A rows 8-15 -> D rows 8-15, never
//      stored; reads stay inside the LDS block).
//  phase0: x -> fp16 LDS xs[64][72]       (region0)
//  phase1: QKV^T = Wqkv^T x^T via 16x16x32_f16 (A=weights, B=x frags cached
//          in regs). Packed C -> qh (Q), kh (K); V scalar -> vth (region0
//          overlay, after the xs-consumed barrier). Barrier (cross-wave).
//  phase2: per wave, heads 2w,2w+1 with 16x16x16_f16 (K=16): A/B frags hold
//          k=4*quad+j == the S^T C-layout, so packed softmax output IS the
//          PV B-operand (no shuffle). S^T col tn: tm<=tn triangular MFMAs;
//          max-free softmax e=exp2(s) (scale pre-folded), causal cndmask on
//          diagonal, tree row-sum + shfl_xor(16,32); O^T = V^T P;
//          normalize by rcp; att -> qh.
//  phase3: y^T = W1^T att^T (16x16x32_f16) -> float4 stores.
// LDS: region0 9216 (xs|vth) + qh 8192 + kh 8192 = 25600 B -> 6 blocks/CU.

typedef __attribute__((ext_vector_type(8))) __fp16 half8;
typedef __attribute__((ext_vector_type(4))) __fp16 half4;
typedef __attribute__((ext_vector_type(2))) __fp16 half2v;
typedef __attribute__((ext_vector_type(4))) float f32x4;

__global__ void prep_weights(const float* __restrict__ Wq,
                             const float* __restrict__ Wk,
                             const float* __restrict__ Wv,
                             const float* __restrict__ W1,
                             __fp16* __restrict__ ws)
{
    int i = blockIdx.x * 256 + threadIdx.x;      // 16384 total
    if (i < 12288) {
        int n = i >> 6, c = i & 63;
        int sec = n >> 6;
        const float* src = (sec == 0) ? Wq : (sec == 1) ? Wk : Wv;
        int h = (n & 63) >> 3, d = n & 7;
        float v = src[h * 512 + c * 8 + d];
        if (sec == 1) v *= 0.18033688011112042f;   // C^-0.5 * log2(e) into K
        ws[i] = (__fp16)v;
    } else {
        int j = (i - 12288) >> 6, c = i & 63;
        ws[i] = (__fp16)W1[c * 64 + j];
    }
}

__device__ __forceinline__ uint32_t pk2h(float a, float b) {
    half2v h = __builtin_amdgcn_cvt_pkrtz(a, b);
    union { half2v h; uint32_t u; } c;
    c.h = h;
    return c.u;
}

__global__ __launch_bounds__(256, 6) void mha_mfma4_kernel(
    const float* __restrict__ x,
    const __fp16* __restrict__ wT,
    const float* __restrict__ b1v,
    float* __restrict__ y)
{
    __shared__ __align__(16) __fp16 region0[64 * 72]; // xs, later vth
    __shared__ __align__(16) __fp16 qh[8 * 64 * 8];   // Q[h][t][d] -> att
    __shared__ __align__(16) __fp16 kh[8 * 64 * 8];   // K[h][s][d]

    __fp16* xs  = region0;            // [64][72]
    __fp16* vth = region0;            // V^T[h][d][s], [64][72] overlay

    const int b    = blockIdx.x;
    const int tid  = threadIdx.x;
    const int lane = tid & 63;
    const int w    = tid >> 6;
    const int l15  = lane & 15;
    const int quad = lane >> 4;

    // ---------------- phase 0: stage x -> fp16 ----------------
    {
        int r = tid >> 2, c0 = (tid & 3) * 16;
        const float* xp = x + (size_t)b * 4096 + r * 64 + c0;
        float4 f0 = ((const float4*)xp)[0];
        float4 f1 = ((const float4*)xp)[1];
        float4 f2 = ((const float4*)xp)[2];
        float4 f3 = ((const float4*)xp)[3];
        union { half2v h2[4]; float4 f; } u0, u1;
        u0.h2[0] = __builtin_amdgcn_cvt_pkrtz(f0.x, f0.y);
        u0.h2[1] = __builtin_amdgcn_cvt_pkrtz(f0.z, f0.w);
        u0.h2[2] = __builtin_amdgcn_cvt_pkrtz(f1.x, f1.y);
        u0.h2[3] = __builtin_amdgcn_cvt_pkrtz(f1.z, f1.w);
        u1.h2[0] = __builtin_amdgcn_cvt_pkrtz(f2.x, f2.y);
        u1.h2[1] = __builtin_amdgcn_cvt_pkrtz(f2.z, f2.w);
        u1.h2[2] = __builtin_amdgcn_cvt_pkrtz(f3.x, f3.y);
        u1.h2[3] = __builtin_amdgcn_cvt_pkrtz(f3.z, f3.w);
        *(float4*)&xs[r * 72 + c0]     = u0.f;
        *(float4*)&xs[r * 72 + c0 + 8] = u1.f;
    }
    __syncthreads();

    // ---------------- phase 1: QKV^T = Wqkv^T x^T ----------------
    {
        half8 xfr[4][2];   // B-frags (x)
        #pragma unroll
        for (int tt = 0; tt < 4; ++tt)
            #pragma unroll
            for (int ks = 0; ks < 2; ++ks)
                xfr[tt][ks] = *(const half8*)&xs[(16 * tt + l15) * 72 + 32 * ks + 8 * quad];
        __syncthreads();    // xs fully consumed; region0 now writable as vth

        #pragma unroll
        for (int i = 0; i < 3; ++i) {
            int mt = 3 * w + i;                       // m-tile over n=0..191
            const __fp16* ap = wT + (16 * mt + l15) * 64 + 8 * quad;
            half8 a0 = *(const half8*)ap;
            half8 a1 = *(const half8*)(ap + 32);
            #pragma unroll
            for (int tt = 0; tt < 4; ++tt) {
                f32x4 acc = {0.f, 0.f, 0.f, 0.f};
                acc = __builtin_amdgcn_mfma_f32_16x16x32_f16(a0, xfr[tt][0], acc, 0, 0, 0);
                acc = __builtin_amdgcn_mfma_f32_16x16x32_f16(a1, xfr[tt][1], acc, 0, 0, 0);
                // thread holds n = 16mt+4quad+r, t = 16tt+l15
                int t = 16 * tt + l15;
                union { uint32_t u2[2]; uint2 u; } pq;
                pq.u2[0] = pk2h(acc[0], acc[1]);
                pq.u2[1] = pk2h(acc[2], acc[3]);
                if (mt < 4) {
                    int hq = 2 * mt + (quad >> 1);
                    *(uint2*)&qh[(hq * 64 + t) * 8 + 4 * (quad & 1)] = pq.u;
                } else if (mt < 8) {
                    int hk = 2 * (mt - 4) + (quad >> 1);
                    *(uint2*)&kh[(hk * 64 + t) * 8 + 4 * (quad & 1)] = pq.u;
                } else {
                    int hv = 2 * (mt - 8) + (quad >> 1);
                    int d0 = 4 * (quad & 1);
                    #pragma unroll
                    for (int r = 0; r < 4; ++r)
                        vth[(hv * 8 + d0 + r) * 72 + t] = (__fp16)acc[r];
                }
            }
        }
    }
    __syncthreads();

    const half4 z4 = {};
    const bool dv = (quad < 2);                      // quads holding valid d (0..7)
    // causal mask predicate per r (lane-constant, hoisted out of the loops)
    bool mrk[4];
    #pragma unroll
    for (int r = 0; r < 4; ++r) mrk[r] = (4 * quad + r) > l15;

    // ---------------- phase 2: attention, heads h = 2w, 2w+1 ----------------
    // 16x16x16_f16: A[m][k]: m=l15, k=4*quad+j.  B[k][n]: n=l15, k=4*quad+j.
    // D[row][col]: row=4*quad+r, col=l15.  S^T output layout == PV B-frag layout.
    #pragma unroll 1
    for (int hh = 0; hh < 2; ++hh) {
        const int h = 2 * w + hh;
        half4 kfr[4], vfr[4];
        #pragma unroll
        for (int tm = 0; tm < 4; ++tm)   // A-frag of K: m=s row, k=d=4q+j (q<2)
            kfr[tm] = dv ? *(const half4*)&kh[(h * 64 + 16 * tm + l15) * 8 + 4 * quad] : z4;
        #pragma unroll
        for (int km = 0; km < 4; ++km)   // A-frag of V^T: m=d=l15, k=s=16km+4q+j
            // no l15<8 select: garbage A rows 8-15 only reach D rows 8-15 (unstored);
            // reads stay inside the 25.6KB LDS block.
            vfr[km] = *(const half4*)&vth[(h * 8 + l15) * 72 + 16 * km + 4 * quad];

        #pragma unroll
        for (int tn = 0; tn < 4; ++tn) {
            // raw load: kfr's zero k-slots (quads 2-3) annihilate B there.
            half4 qf = *(const half4*)&qh[(h * 64 + 16 * tn + l15) * 8 + 4 * quad];

            f32x4 S[4];   // S^T tiles in column tn, tm <= tn
            #pragma unroll
            for (int tm = 0; tm <= tn; ++tm) {
                f32x4 zz = {0.f, 0.f, 0.f, 0.f};
                S[tm] = __builtin_amdgcn_mfma_f32_16x16x16f16(kfr[tm], qf, zz, 0, 0, 0);
            }

            // max-free softmax (scores bounded); scale pre-folded into K.
            // Tree-reassociated denominator: pairwise within a tile, two
            // alternating cross-tile accumulators (depth ~5 vs serial 16).
            float acc0 = 0.f, acc1 = 0.f;
            #pragma unroll
            for (int tm = 0; tm <= tn; ++tm) {
                float e0 = __builtin_exp2f(S[tm][0]);
                float e1 = __builtin_exp2f(S[tm][1]);
                float e2 = __builtin_exp2f(S[tm][2]);
                float e3 = __builtin_exp2f(S[tm][3]);
                if (tm == tn) {             // causal mask on the diagonal tile
                    if (mrk[0]) e0 = 0.f;
                    if (mrk[1]) e1 = 0.f;
                    if (mrk[2]) e2 = 0.f;
                    if (mrk[3]) e3 = 0.f;
                }
                S[tm][0] = e0; S[tm][1] = e1; S[tm][2] = e2; S[tm][3] = e3;
                float ts = (e0 + e1) + (e2 + e3);
                if (tm & 1) acc1 += ts; else acc0 += ts;
            }
            float ls = acc0 + acc1;
            ls += __shfl_xor(ls, 16);
            ls += __shfl_xor(ls, 32);
            float inv = __builtin_amdgcn_rcpf(ls);

            // O^T col tn: packed P IS the B-frag (k=4q+j == s layout). No shuffle.
            f32x4 O = {0.f, 0.f, 0.f, 0.f};
            #pragma unroll
            for (int km = 0; km <= tn; ++km) {
                union { uint32_t u[2]; half4 h4; } bu;
                bu.u[0] = pk2h(S[km][0], S[km][1]);
                bu.u[1] = pk2h(S[km][2], S[km][3]);
                O = __builtin_amdgcn_mfma_f32_16x16x16f16(vfr[km], bu.h4, O, 0, 0, 0);
            }

            // O^T: row d=4q+r (valid for q<2), col t=16tn+l15; normalize by own column sum
            if (dv) {
                union { uint32_t u2[2]; uint2 u; } po;
                po.u2[0] = pk2h(O[0] * inv, O[1] * inv);
                po.u2[1] = pk2h(O[2] * inv, O[3] * inv);
                *(uint2*)&qh[(h * 64 + 16 * tn + l15) * 8 + 4 * quad] = po.u;
            }
        }
    }
    __syncthreads();

    // ---------------- phase 3: y^T = W1^T att^T ----------------
    {
        const __fp16* wp = wT + 12288 + (16 * w + l15) * 64 + 8 * quad;
        half8 w0 = *(const half8*)wp;
        half8 w1 = *(const half8*)(wp + 32);
        float4 bias4 = *(const float4*)&b1v[16 * w + 4 * quad];
        float* yb = y + (size_t)b * 4096;
        #pragma unroll
        for (int tt = 0; tt < 4; ++tt) {
            half8 bq0 = *(const half8*)&qh[(quad * 64 + 16 * tt + l15) * 8];       // k: h=quad
            half8 bq1 = *(const half8*)&qh[((4 + quad) * 64 + 16 * tt + l15) * 8]; // k: h=4+quad
            f32x4 acc = {0.f, 0.f, 0.f, 0.f};
            acc = __builtin_amdgcn_mfma_f32_16x16x32_f16(w0, bq0, acc, 0, 0, 0);
            acc = __builtin_amdgcn_mfma_f32_16x16x32_f16(w1, bq1, acc, 0, 0, 0);
            float4 o;
            o.x = fmaxf(acc[0] + bias4.x, 0.f);
            o.y = fmaxf(acc[1] + bias4.y, 0.f);
            o.z = fmaxf(acc[2] + bias4.z, 0.f);
            o.w = fmaxf(acc[3] + bias4.w, 0.f);
            *(float4*)&yb[(16 * tt + l15) * 64 + 16 * w + 4 * quad] = o;
        }
    }
}

extern "C" void kernel_launch(void* const* d_in, const int* in_sizes, int n_in,
                              void* d_out, int out_size, void* d_ws, size_t ws_size,
                              hipStream_t stream) {
    const float* x  = (const float*)d_in[0];
    const float* Wq = (const float*)d_in[1];
    const float* Wk = (const float*)d_in[2];
    const float* Wv = (const float*)d_in[3];
    const float* W1 = (const float*)d_in[4];
    const float* b1 = (const float*)d_in[5];
    float* y = (float*)d_out;
    __fp16* ws = (__fp16*)d_ws;

    const int B = in_sizes[0] / 4096;   // 4096
    prep_weights<<<64, 256, 0, stream>>>(Wq, Wk, Wv, W1, ws);
    mha_mfma4_kernel<<<B, 256, 0, stream>>>(x, ws, b1, y);
}